// Round 10
// baseline (161.981 us; speedup 1.0000x reference)
//
#include <hip/hip_runtime.h>
#include <hip/hip_bf16.h>
#include <stdint.h>

// out = tril(Q K^T) * scale @ V  (no softmax), Q/K/V = x @ W^T + b
// B=4, N=2048, D=1024, f32 in/out; bf16 MFMA, f32 accum.
// Unified GEMM: 128x128 tile, BK=32, 256 thr (4 waves), depth-4 counted-vmcnt
// pipeline, 5-slot ring, 80 KiB LDS -> exactly 2 blocks/CU.

typedef __attribute__((ext_vector_type(4))) float f32x4;
typedef __attribute__((ext_vector_type(8))) short bf16x8s;
typedef __attribute__((ext_vector_type(4))) short bf16x4s;

__device__ __forceinline__ short f2bf(float f) {
  union { float f; unsigned u; } v; v.f = f;
  return (short)((v.u + 0x7FFFu + ((v.u >> 16) & 1u)) >> 16);  // RNE
}

// ---------------- fused cast f32 -> bf16 ----------------
__global__ void cast_all(const float* __restrict__ x, const float* __restrict__ wq,
                         const float* __restrict__ wk, const float* __restrict__ wv,
                         short* __restrict__ xb, short* __restrict__ wcat) {
  const int n4x = 1 << 21;
  const int n4w = 1 << 18;
  const int total = n4x + 3 * n4w;
  int idx = blockIdx.x * blockDim.x + threadIdx.x;
  int stride = gridDim.x * blockDim.x;
  for (int i = idx; i < total; i += stride) {
    f32x4 v;
    short* dst;
    if (i < n4x) {
      v = ((const f32x4*)x)[i];
      dst = xb + (size_t)i * 4;
    } else {
      int j = i - n4x;
      int sel = j >> 18, off = j & (n4w - 1);
      const float* src = (sel == 0) ? wq : (sel == 1) ? wk : wv;
      v = ((const f32x4*)src)[off];
      dst = wcat + (size_t)j * 4;
    }
    bf16x4s o;
    o[0] = f2bf(v[0]); o[1] = f2bf(v[1]); o[2] = f2bf(v[2]); o[3] = f2bf(v[3]);
    *(bf16x4s*)dst = o;
  }
}

// ---------------- staging / fragment reads ----------------
// Slot = 128 rows x 32 K bf16 = 8 KB. Swizzle: 16B-granule g ^= (row>>1)&3;
// inverse applied on global source (involution), applied on ds_read.
// 256 threads: granule id = e*256 + wid*64 + lane; row = id>>2.

#define STG(gp, ld_, kelem, slot)                                                     \
  {                                                                                   \
    const int gsrc_ = (((lane & 3) ^ ((lane >> 3) & 3)) << 3);                        \
    _Pragma("unroll") for (int e_ = 0; e_ < 2; ++e_) {                                \
      int row_ = e_ * 64 + wid * 16 + (lane >> 2);                                    \
      const short* src_ = (gp) + (size_t)row_ * (ld_) + (kelem) + gsrc_;              \
      __builtin_amdgcn_global_load_lds(                                               \
          (const __attribute__((address_space(1))) void*)src_,                        \
          (__attribute__((address_space(3))) void*)((slot) + e_ * 2048 + wid * 512),  \
          16, 0, 0);                                                                  \
    }                                                                                 \
  }

#define LDSF(slot, row) \
  (*(const bf16x8s*)&(slot)[(row) * 32 + ((kq ^ (((row) >> 1) & 3)) << 3)])

// ========== 128x128 / BK=32 / depth-4 counted-vmcnt pipelined GEMM ==========
// 256 threads = 4 waves (2m x 2n), 64x64 out/wave, acc[4][4].
// LDS: 5 ring slots x (A 8KB + B 8KB) = 80 KiB -> 2 blocks/CU.
// Tile T: STAGE(T+4) -> ds_read(T) -> lgkm -> MFMA -> vmcnt(12|8|4|0) -> barrier.

// MODE 0: QKV. A=xb[8192,1024], B=Wcat[3072,1024]; epilogue seg -> Qb/Kb/Vt.
// MODE 2: scores. per-batch triangular 128x128; epilogue mask+scale -> Sb (bf16).
// MODE 3: PV. A=Sb[2048,2048], B=Vt[1024,2048]; NT=(qt+1)*4; f32 -> O.
template <int MODE>
__global__ __launch_bounds__(256, 2) void gemm128(
    const short* __restrict__ A, const short* __restrict__ Bm,
    const float* __restrict__ bq, const float* __restrict__ bk,
    const float* __restrict__ bv, short* __restrict__ Qb,
    short* __restrict__ Kb, short* __restrict__ Vt,
    short* __restrict__ Sb, float* __restrict__ O, float scale) {
  const int ld = (MODE == 3) ? 2048 : 1024;
  int tx, ty, NTv;
  const short *Abase, *Bbase;
  long long bz = 0;
  if (MODE == 0) {
    int id = blockIdx.x;                 // 1536 blocks; XCD-bijective (1536 = 8*192)
    int swz = (id & 7) * 192 + (id >> 3);
    tx = swz % 24; ty = swz / 24;        // ty: 128-row A tile, tx: 128-row B tile
    Abase = A; Bbase = Bm;
    NTv = 32;
  } else if (MODE == 2) {
    bz = blockIdx.z;
    int id = blockIdx.x;                 // 136 tiles (128x128); 136 = 8*17
    int ti = (id & 7) * 17 + (id >> 3);
    int qt = 0, c = 0;
    while (c + qt + 1 <= ti) { c += qt + 1; ++qt; }
    ty = qt; tx = ti - c;                // tx <= ty
    Abase = A + bz * (2048LL * 1024LL);
    Bbase = Bm + bz * (2048LL * 1024LL);
    NTv = 32;
  } else {
    bz = blockIdx.z;
    int id = blockIdx.x;                 // 128 tiles: 16 qt x 8 et
    tx = id & 7;                         // e-tile
    ty = 15 - (id >> 3);                 // longest-first
    Abase = A + bz * (2048LL * 2048LL);
    Bbase = Bm + bz * (1024LL * 2048LL);
    NTv = (ty + 1) * 4;                  // Kend = (ty+1)*128
  }
  const short* Ap = Abase + (size_t)(ty * 128) * ld;
  const short* Bp = Bbase + (size_t)(tx * 128) * ld;

  __shared__ short lds[40960];  // 80 KiB: A slot s @ s*4096, B slot s @ 20480+s*4096

  const int tid = threadIdx.x;
  const int wid = tid >> 6, lane = tid & 63;
  const int wm = wid >> 1, wn = wid & 1;   // 2 x 2 waves, 64x64 out each
  const int kq = lane >> 4, r16 = lane & 15;

  f32x4 acc[4][4];
#pragma unroll
  for (int i = 0; i < 4; ++i)
#pragma unroll
    for (int j = 0; j < 4; ++j) { f32x4 z = {0.f, 0.f, 0.f, 0.f}; acc[i][j] = z; }

  // prologue: stage tiles 0..3 into slots 0..3 (NTv >= 4 always)
#pragma unroll
  for (int p = 0; p < 4; ++p) {
    STG(Ap, ld, p * 32, (lds + p * 4096));
    STG(Bp, ld, p * 32, (lds + 20480 + p * 4096));
  }
  asm volatile("s_waitcnt vmcnt(12)" ::: "memory");  // tile 0 landed
  __builtin_amdgcn_s_barrier();

  int cs = 0, ss = 4;  // consume slot, stage slot (= (cs+4)%5)
  for (int T = 0; T < NTv; ++T) {
    if (T + 4 < NTv) {
      STG(Ap, ld, (T + 4) * 32, (lds + ss * 4096));
      STG(Bp, ld, (T + 4) * 32, (lds + 20480 + ss * 4096));
    }
    const short* curA = lds + cs * 4096;
    const short* curB = lds + 20480 + cs * 4096;
    bf16x8s a_[4], b_[4];
#pragma unroll
    for (int mi = 0; mi < 4; ++mi)
      a_[mi] = LDSF(curA, wm * 64 + mi * 16 + r16);
#pragma unroll
    for (int nj = 0; nj < 4; ++nj)
      b_[nj] = LDSF(curB, wn * 64 + nj * 16 + r16);
    asm volatile("s_waitcnt lgkmcnt(0)" ::: "memory");
    __builtin_amdgcn_s_setprio(1);
#pragma unroll
    for (int mi = 0; mi < 4; ++mi)
#pragma unroll
      for (int nj = 0; nj < 4; ++nj)
        acc[mi][nj] = __builtin_amdgcn_mfma_f32_16x16x32_bf16(a_[mi], b_[nj], acc[mi][nj], 0, 0, 0);
    __builtin_amdgcn_s_setprio(0);
    // guarantee tile T+1 landed; keep newer stages in flight (4 loads/tile)
    const int rem = NTv - T;
    if (rem > 4) {
      asm volatile("s_waitcnt vmcnt(12)" ::: "memory");
    } else if (rem == 4) {
      asm volatile("s_waitcnt vmcnt(8)" ::: "memory");
    } else if (rem == 3) {
      asm volatile("s_waitcnt vmcnt(4)" ::: "memory");
    } else {
      asm volatile("s_waitcnt vmcnt(0)" ::: "memory");
    }
    __builtin_amdgcn_s_barrier();
    cs = (cs + 1 == 5) ? 0 : cs + 1;
    ss = (ss + 1 == 5) ? 0 : ss + 1;
  }

  // ---- epilogue ----
  const int rowt0 = ty * 128 + wm * 64;
  if (MODE == 0) {
    const int seg = tx >> 3;                       // 0:Q 1:K 2:V
    const int colseg0 = (tx & 7) * 128 + wn * 64;  // col within 1024 segment
    if (seg < 2) {
      short* Cb = (seg == 0) ? Qb : Kb;
      const float* bias = (seg == 0) ? bq : bk;
#pragma unroll
      for (int mf = 0; mf < 4; ++mf) {
#pragma unroll
        for (int nj = 0; nj < 4; ++nj) {
          int col = colseg0 + nj * 16 + r16;
          float bvv = bias[col];
#pragma unroll
          for (int rr = 0; rr < 4; ++rr) {
            int row = rowt0 + mf * 16 + kq * 4 + rr;
            Cb[(size_t)row * 1024 + col] = f2bf(acc[mf][nj][rr] + bvv);
          }
        }
      }
    } else {
      // Vt[b][e][n]
#pragma unroll
      for (int mf = 0; mf < 4; ++mf) {
        int rowg = rowt0 + mf * 16 + kq * 4;
        int b = rowg >> 11, n0 = rowg & 2047;
        long long base = (long long)b * (1024LL * 2048LL);
#pragma unroll
        for (int nj = 0; nj < 4; ++nj) {
          int col = colseg0 + nj * 16 + r16;
          float bvv = bv[col];
          bf16x4s o;
#pragma unroll
          for (int rr = 0; rr < 4; ++rr) o[rr] = f2bf(acc[mf][nj][rr] + bvv);
          *(bf16x4s*)&Vt[base + (long long)col * 2048 + n0] = o;
        }
      }
    }
  } else if (MODE == 2) {
    short* Cb = Sb + bz * (2048LL * 2048LL);
    const int colt0 = tx * 128 + wn * 64;
#pragma unroll
    for (int mf = 0; mf < 4; ++mf) {
#pragma unroll
      for (int nj = 0; nj < 4; ++nj) {
        int col = colt0 + nj * 16 + r16;
#pragma unroll
        for (int rr = 0; rr < 4; ++rr) {
          int row = rowt0 + mf * 16 + kq * 4 + rr;
          float v = (col <= row) ? acc[mf][nj][rr] * scale : 0.0f;
          Cb[(size_t)row * 2048 + col] = f2bf(v);
        }
      }
    }
  } else {
    float* Cb = O + bz * (2048LL * 1024LL);
    const int colt0 = tx * 128 + wn * 64;
#pragma unroll
    for (int mf = 0; mf < 4; ++mf) {
#pragma unroll
      for (int nj = 0; nj < 4; ++nj) {
        int col = colt0 + nj * 16 + r16;
#pragma unroll
        for (int rr = 0; rr < 4; ++rr) {
          int row = rowt0 + mf * 16 + kq * 4 + rr;
          Cb[(size_t)row * 1024 + col] = acc[mf][nj][rr];
        }
      }
    }
  }
}

extern "C" void kernel_launch(void* const* d_in, const int* in_sizes, int n_in,
                              void* d_out, int out_size, void* d_ws, size_t ws_size,
                              hipStream_t stream) {
  const float* x  = (const float*)d_in[0];
  const float* Wq = (const float*)d_in[1];
  const float* bq = (const float*)d_in[2];
  const float* Wk = (const float*)d_in[3];
  const float* bk = (const float*)d_in[4];
  const float* Wv = (const float*)d_in[5];
  const float* bv = (const float*)d_in[6];

  const int B = 4;
  const long long MB = 1LL << 20;

  char* ws = (char*)d_ws;
  short* Qb   = (short*)(ws + 0 * MB);   // 16 MB bf16 Q [8192,1024]
  short* Kb   = (short*)(ws + 16 * MB);  // 16 MB bf16 K
  short* Vt   = (short*)(ws + 32 * MB);  // 16 MB bf16 V^T [4][1024][2048]
  short* xb   = (short*)(ws + 48 * MB);  // 16 MB bf16 x     (dead after QKV)
  short* Wcat = (short*)(ws + 64 * MB);  // 6 MB  bf16 [Wq;Wk;Wv] (dead after QKV)
  short* Sb   = (short*)(ws + 48 * MB);  // 32 MB scores, reuses xb/Wcat

  // 1. fused casts
  cast_all<<<2048, 256, 0, stream>>>(x, Wq, Wk, Wv, xb, Wcat);

  // 2. fused QKV projection: [8192,3072] = xb @ Wcat^T ; 1536 blocks = 3 rounds
  gemm128<0><<<1536, 256, 0, stream>>>(xb, Wcat, bq, bk, bv, Qb, Kb, Vt,
                                       nullptr, nullptr, 1.0f);

  // 3. scores: per batch S = tril(Q K^T) / 32, 136 (128x128) tiles x 4 batches
  dim3 g2(136, 1, B);
  gemm128<2><<<g2, 256, 0, stream>>>(Qb, Kb, nullptr, nullptr, nullptr, nullptr,
                                     nullptr, nullptr, Sb, nullptr, 0.03125f);

  // 4. PV: per batch O = S @ Vt^T, causal K-extent, longest-first; 512 blocks
  dim3 g3(128, 1, B);
  gemm128<3><<<g3, 256, 0, stream>>>(Sb, Vt, nullptr, nullptr, nullptr, nullptr,
                                     nullptr, nullptr, nullptr, (float*)d_out, 1.0f);
}

// Round 11
// 149.746 us; speedup vs baseline: 1.0817x; 1.0817x over previous
//
#include <hip/hip_runtime.h>
#include <hip/hip_bf16.h>
#include <stdint.h>

// out = tril(Q K^T) * scale @ V  (no softmax), Q/K/V = x @ W^T + b
// B=4, N=2048, D=1024, f32 in/out; bf16 MFMA, f32 accum.
// All GEMMs: 128x256 tile, BK=32, 256 thr / 4 waves (64x128 out per wave),
// depth-2 counted-vmcnt ring (3 slots, 72 KiB LDS), 2 blocks/CU.

typedef __attribute__((ext_vector_type(4))) float f32x4;
typedef __attribute__((ext_vector_type(8))) short bf16x8s;
typedef __attribute__((ext_vector_type(4))) short bf16x4s;

__device__ __forceinline__ short f2bf(float f) {
  union { float f; unsigned u; } v; v.f = f;
  return (short)((v.u + 0x7FFFu + ((v.u >> 16) & 1u)) >> 16);  // RNE
}

// ---------------- fused cast f32 -> bf16 ----------------
__global__ void cast_all(const float* __restrict__ x, const float* __restrict__ wq,
                         const float* __restrict__ wk, const float* __restrict__ wv,
                         short* __restrict__ xb, short* __restrict__ wcat) {
  const int n4x = 1 << 21;
  const int n4w = 1 << 18;
  const int total = n4x + 3 * n4w;
  int idx = blockIdx.x * blockDim.x + threadIdx.x;
  int stride = gridDim.x * blockDim.x;
  for (int i = idx; i < total; i += stride) {
    f32x4 v;
    short* dst;
    if (i < n4x) {
      v = ((const f32x4*)x)[i];
      dst = xb + (size_t)i * 4;
    } else {
      int j = i - n4x;
      int sel = j >> 18, off = j & (n4w - 1);
      const float* src = (sel == 0) ? wq : (sel == 1) ? wk : wv;
      v = ((const f32x4*)src)[off];
      dst = wcat + (size_t)j * 4;
    }
    bf16x4s o;
    o[0] = f2bf(v[0]); o[1] = f2bf(v[1]); o[2] = f2bf(v[2]); o[3] = f2bf(v[3]);
    *(bf16x4s*)dst = o;
  }
}

// ---------------- staging / fragment reads (256 threads) ----------------
// Swizzle: 16B-granule g ^= (row>>1)&3; inverse on global src, applied on ds_read.
// row_ = e*64 + wid*16 + (lane>>2); (row>>1)&3 == (tid>>3)&3 since e*64 rows.

// stage 128 rows x 32 K (8 KB): 2 gload_lds(16B)/thread
#define STG_A(gp, ld_, kelem, slot)                                                   \
  {                                                                                   \
    const int gsrc_ = (((tid & 3) ^ ((tid >> 3) & 3)) << 3);                          \
    _Pragma("unroll") for (int e_ = 0; e_ < 2; ++e_) {                                \
      int row_ = e_ * 64 + wid * 16 + (lane >> 2);                                    \
      const short* src_ = (gp) + (size_t)row_ * (ld_) + (kelem) + gsrc_;              \
      __builtin_amdgcn_global_load_lds(                                               \
          (const __attribute__((address_space(1))) void*)src_,                        \
          (__attribute__((address_space(3))) void*)((slot) + e_ * 2048 + wid * 512),  \
          16, 0, 0);                                                                  \
    }                                                                                 \
  }

// stage 256 rows x 32 K (16 KB): 4 gload_lds(16B)/thread
#define STG_B(gp, ld_, kelem, slot)                                                   \
  {                                                                                   \
    const int gsrc_ = (((tid & 3) ^ ((tid >> 3) & 3)) << 3);                          \
    _Pragma("unroll") for (int e_ = 0; e_ < 4; ++e_) {                                \
      int row_ = e_ * 64 + wid * 16 + (lane >> 2);                                    \
      const short* src_ = (gp) + (size_t)row_ * (ld_) + (kelem) + gsrc_;              \
      __builtin_amdgcn_global_load_lds(                                               \
          (const __attribute__((address_space(1))) void*)src_,                        \
          (__attribute__((address_space(3))) void*)((slot) + e_ * 2048 + wid * 512),  \
          16, 0, 0);                                                                  \
    }                                                                                 \
  }

#define LDSF(slot, row) \
  (*(const bf16x8s*)&(slot)[(row) * 32 + ((kq ^ (((row) >> 1) & 3)) << 3)])

// ========== 128x256 / BK=32 / depth-2 ring, 4 waves of 64x128 out ==========
// LDS: A slots 4096 shorts @ s*4096 (s<3); B slots 8192 shorts @ 12288+s*8192.
// Tile T: STAGE(T+2) -> ds_read(T) [4 A + 8 B frags] -> lgkm -> 32 MFMA
//         -> vmcnt(6) [T+1 landed] -> barrier.   6 loads/thread/tile.

template <int MODE>
__device__ __forceinline__ void gemm_body(
    const short* __restrict__ A, const short* __restrict__ Bm,
    const float* __restrict__ bq, const float* __restrict__ bk,
    const float* __restrict__ bv, short* __restrict__ Qb,
    short* __restrict__ Kb, short* __restrict__ Vt,
    short* __restrict__ Sb, float* __restrict__ O, float scale) {
  const int ld = (MODE == 3) ? 2048 : 1024;
  int tx, ty, NTv;
  const short *Abase, *Bbase;
  long long bz = 0;
  if (MODE == 0) {
    int id = blockIdx.x;                 // 768 blocks; XCD-bijective (768 = 8*96)
    int swz = (id & 7) * 96 + (id >> 3);
    tx = swz % 12; ty = swz / 12;        // ty: 128-row A tile, tx: 256-row B tile
    Abase = A; Bbase = Bm;
    NTv = 32;
  } else if (MODE == 2) {
    bz = blockIdx.z;
    int id = blockIdx.x;                 // 72 tiles (128q x 256k); 72 = 8*9
    int ti = (id & 7) * 9 + (id >> 3);
    int qt = 0, c = 0;
    while (c + (qt / 2 + 1) <= ti) { c += qt / 2 + 1; ++qt; }
    ty = qt; tx = ti - c;
    Abase = A + bz * (2048LL * 1024LL);
    Bbase = Bm + bz * (2048LL * 1024LL);
    NTv = 32;
  } else {
    bz = blockIdx.z;
    int id = blockIdx.x;                 // 64 tiles: 16 q-tiles x 4 e-tiles
    tx = id & 3;
    ty = 15 - (id >> 2);                 // longest-first
    Abase = A + bz * (2048LL * 2048LL);
    Bbase = Bm + bz * (1024LL * 2048LL);
    NTv = (ty + 1) * 4;                  // Kend = (ty+1)*128
  }
  const short* Ap = Abase + (size_t)(ty * 128) * ld;
  const short* Bp = Bbase + (size_t)(tx * 256) * ld;

  __shared__ short lds[36864];  // 72 KiB

  const int tid = threadIdx.x;
  const int wid = tid >> 6, lane = tid & 63;
  const int wm = wid >> 1, wn = wid & 1;   // 2m x 2n waves, 64x128 out each
  const int kq = lane >> 4, r16 = lane & 15;

  f32x4 acc[4][8];
#pragma unroll
  for (int i = 0; i < 4; ++i)
#pragma unroll
    for (int j = 0; j < 8; ++j) { f32x4 z = {0.f, 0.f, 0.f, 0.f}; acc[i][j] = z; }

  // prologue: stage tiles 0,1 into slots 0,1; wait tile 0 (6 newer in flight)
  STG_A(Ap, ld, 0, (lds + 0));
  STG_B(Bp, ld, 0, (lds + 12288));
  STG_A(Ap, ld, 32, (lds + 4096));
  STG_B(Bp, ld, 32, (lds + 12288 + 8192));
  asm volatile("s_waitcnt vmcnt(6)" ::: "memory");
  __builtin_amdgcn_s_barrier();

  int cs = 0;  // slot of tile T
  for (int T = 0; T < NTv; ++T) {
    int ns = cs + 2; if (ns >= 3) ns -= 3;   // slot of tile T+2
    if (T + 2 < NTv) {
      STG_A(Ap, ld, (T + 2) * 32, (lds + ns * 4096));
      STG_B(Bp, ld, (T + 2) * 32, (lds + 12288 + ns * 8192));
    }
    const short* curA = lds + cs * 4096;
    const short* curB = lds + 12288 + cs * 8192;
    bf16x8s a_[4], b_[8];
#pragma unroll
    for (int mi = 0; mi < 4; ++mi)
      a_[mi] = LDSF(curA, wm * 64 + mi * 16 + r16);
#pragma unroll
    for (int nj = 0; nj < 8; ++nj)
      b_[nj] = LDSF(curB, wn * 128 + nj * 16 + r16);
    asm volatile("s_waitcnt lgkmcnt(0)" ::: "memory");
    __builtin_amdgcn_s_setprio(1);
#pragma unroll
    for (int mi = 0; mi < 4; ++mi)
#pragma unroll
      for (int nj = 0; nj < 8; ++nj)
        acc[mi][nj] = __builtin_amdgcn_mfma_f32_16x16x32_bf16(a_[mi], b_[nj], acc[mi][nj], 0, 0, 0);
    __builtin_amdgcn_s_setprio(0);
    if (T < NTv - 2) {
      asm volatile("s_waitcnt vmcnt(6)" ::: "memory");  // tile T+1 landed
    } else {
      asm volatile("s_waitcnt vmcnt(0)" ::: "memory");  // tail drain
    }
    __builtin_amdgcn_s_barrier();
    cs = (cs + 1 == 3) ? 0 : cs + 1;
  }

  // ---- epilogue ----
  const int rowt0 = ty * 128 + wm * 64;
  if (MODE == 0) {
    const int seg = tx >> 2;                                  // 0:Q 1:K 2:V
    const int colseg0 = (tx & 3) * 256 + wn * 128;            // within 1024 segment
    if (seg < 2) {
      short* Cb = (seg == 0) ? Qb : Kb;
      const float* bias = (seg == 0) ? bq : bk;
#pragma unroll
      for (int mf = 0; mf < 4; ++mf) {
#pragma unroll
        for (int nj = 0; nj < 8; ++nj) {
          int col = colseg0 + nj * 16 + r16;
          float bvv = bias[col];
#pragma unroll
          for (int rr = 0; rr < 4; ++rr) {
            int row = rowt0 + mf * 16 + kq * 4 + rr;
            Cb[(size_t)row * 1024 + col] = f2bf(acc[mf][nj][rr] + bvv);
          }
        }
      }
    } else {
      // Vt[b][e][n]
#pragma unroll
      for (int mf = 0; mf < 4; ++mf) {
        int rowg = rowt0 + mf * 16 + kq * 4;
        int b = rowg >> 11, n0 = rowg & 2047;
        long long base = (long long)b * (1024LL * 2048LL);
#pragma unroll
        for (int nj = 0; nj < 8; ++nj) {
          int col = colseg0 + nj * 16 + r16;
          float bvv = bv[col];
          bf16x4s o;
#pragma unroll
          for (int rr = 0; rr < 4; ++rr) o[rr] = f2bf(acc[mf][nj][rr] + bvv);
          *(bf16x4s*)&Vt[base + (long long)col * 2048 + n0] = o;
        }
      }
    }
  } else if (MODE == 2) {
    short* Cb = Sb + bz * (2048LL * 2048LL);
    const int colt0 = tx * 256 + wn * 128;
#pragma unroll
    for (int mf = 0; mf < 4; ++mf) {
#pragma unroll
      for (int nj = 0; nj < 8; ++nj) {
        int col = colt0 + nj * 16 + r16;
#pragma unroll
        for (int rr = 0; rr < 4; ++rr) {
          int row = rowt0 + mf * 16 + kq * 4 + rr;
          float v = (col <= row) ? acc[mf][nj][rr] * scale : 0.0f;
          Cb[(size_t)row * 2048 + col] = f2bf(v);
        }
      }
    }
  } else {
    float* Cb = O + bz * (2048LL * 1024LL);
    const int colt0 = tx * 256 + wn * 128;
#pragma unroll
    for (int mf = 0; mf < 4; ++mf) {
#pragma unroll
      for (int nj = 0; nj < 8; ++nj) {
        int col = colt0 + nj * 16 + r16;
#pragma unroll
        for (int rr = 0; rr < 4; ++rr) {
          int row = rowt0 + mf * 16 + kq * 4 + rr;
          Cb[(size_t)row * 1024 + col] = acc[mf][nj][rr];
        }
      }
    }
  }
}

__global__ __launch_bounds__(256, 2) void k_qkv(
    const short* __restrict__ A, const short* __restrict__ Bm,
    const float* __restrict__ bq, const float* __restrict__ bk,
    const float* __restrict__ bv, short* __restrict__ Qb,
    short* __restrict__ Kb, short* __restrict__ Vt) {
  gemm_body<0>(A, Bm, bq, bk, bv, Qb, Kb, Vt, nullptr, nullptr, 1.0f);
}

__global__ __launch_bounds__(256, 2) void k_scores(
    const short* __restrict__ Q, const short* __restrict__ K,
    short* __restrict__ Sb, float scale) {
  gemm_body<2>(Q, K, nullptr, nullptr, nullptr, nullptr, nullptr, nullptr,
               Sb, nullptr, scale);
}

__global__ __launch_bounds__(256, 2) void k_pv(
    const short* __restrict__ S, const short* __restrict__ Vt,
    float* __restrict__ O) {
  gemm_body<3>(S, Vt, nullptr, nullptr, nullptr, nullptr, nullptr, nullptr,
               nullptr, O, 1.0f);
}

extern "C" void kernel_launch(void* const* d_in, const int* in_sizes, int n_in,
                              void* d_out, int out_size, void* d_ws, size_t ws_size,
                              hipStream_t stream) {
  const float* x  = (const float*)d_in[0];
  const float* Wq = (const float*)d_in[1];
  const float* bq = (const float*)d_in[2];
  const float* Wk = (const float*)d_in[3];
  const float* bk = (const float*)d_in[4];
  const float* Wv = (const float*)d_in[5];
  const float* bv = (const float*)d_in[6];

  const int B = 4;
  const long long MB = 1LL << 20;

  char* ws = (char*)d_ws;
  short* Qb   = (short*)(ws + 0 * MB);   // 16 MB bf16 Q [8192,1024]
  short* Kb   = (short*)(ws + 16 * MB);  // 16 MB bf16 K
  short* Vt   = (short*)(ws + 32 * MB);  // 16 MB bf16 V^T [4][1024][2048]
  short* xb   = (short*)(ws + 48 * MB);  // 16 MB bf16 x     (dead after QKV)
  short* Wcat = (short*)(ws + 64 * MB);  // 6 MB  bf16 [Wq;Wk;Wv] (dead after QKV)
  short* Sb   = (short*)(ws + 48 * MB);  // 32 MB scores, reuses xb/Wcat

  // 1. fused casts
  cast_all<<<2048, 256, 0, stream>>>(x, Wq, Wk, Wv, xb, Wcat);

  // 2. fused QKV projection: [8192,3072] = xb @ Wcat^T ; 768 blocks
  k_qkv<<<768, 256, 0, stream>>>(xb, Wcat, bq, bk, bv, Qb, Kb, Vt);

  // 3. scores: per batch S = tril(Q K^T) / 32, 72 (128x256) tiles x 4 batches
  dim3 g2(72, 1, B);
  k_scores<<<g2, 256, 0, stream>>>(Qb, Kb, Sb, 0.03125f);

  // 4. PV: per batch O = S @ Vt^T, causal K-extent, longest-first
  dim3 g3(64, 1, B);
  k_pv<<<g3, 256, 0, stream>>>(Sb, Vt, (float*)d_out);
}